// Round 2
// 103.091 us; speedup vs baseline: 1.0470x; 1.0470x over previous
//
#include <hip/hip_runtime.h>

// ConvCRF forward, MI355X — round 17: R16 resubmit with poison-robust epochs.
// R16 bench died with an infra-level "container failed twice" (no profile).
// Audit found no deterministic hang in R16, but its epoch scheme depended on
// the poison byte being EXACTLY 0xAA (a silent-wrong-answer tripwire if the
// harness poison differs). R17 = same three optimizations, hardened sync:
//  - epoch word := 0x5EED0000 | seq  (seq = it+1, 16-bit). A poller decodes
//    any word whose hi16 != 0x5EED as seq 0. Byte-uniform poison (0x00/0xAA/
//    0xFF/...) can never alias the tag (0x5E != 0xED), so ANY poison value
//    reads as "not yet published" -> wait for the genuine store. No zeroing
//    pass, no magic spin, no pre-work device round trip.
// Carried from R16 (vs R15 baseline, sync wait-set/ping-pong proof identical):
//  (1) deleted bid0 zeroing + magic handshake entirely (see above).
//  (2) sm0 = softmax(u) is input-only: load u, publish sm0, store epoch seq 1
//      at the TOP of the kernel, before the exp-heavy weight prologue. The
//      iter-0 neighbor poll finds epochs already visible (sync hidden under
//      ~4-5us of prologue). Publish is still drained by __syncthreads (vmcnt0)
//      before the epoch store — ordering mechanism unchanged from R15.
//  (3) LDS sm halo stored f32 (global exchange stays f16 u64 atomics): one
//      convert per staged element instead of 4 cvt per tap (saves ~980
//      v_cvt_f32_f16/thread ≈ 20% of dynamic VALU). Own-tile interior written
//      from f32 softmax registers (MORE precise than R15's f16 round-trip).
//      f32 halo row stride padded to 25 float4.
// Everything else identical: uniform iterations, ring staging + interior
// self-write, diag fast path, LDS tap weights, O(19)/entry M prologue,
// relaxed agent-atomic f16 sm exchange, neighbor-only epoch sync.

typedef __attribute__((ext_vector_type(4))) _Float16 half4;
typedef __attribute__((ext_vector_type(2))) _Float16 half2f;
typedef __attribute__((ext_vector_type(4))) float float4v;

#define HH 160
#define WW 160
#define NPIX (HH*WW)
#define NC 19
#define NG 5
#define SPAN 3
#define TR 8
#define TC 16
#define NPXT 128
#define LR 14              // TR + 2*SPAN
#define LC 22              // TC + 2*SPAN
#define LCP 24             // rgb halo row stride (float4 units)
#define HSTRIDE (LR*LCP)   // 336 (rgb halo, float4 units)
#define LCP_F 25           // f32 sm halo row stride (float4 units)
#define HS_F (LR*LCP_F)    // 350
#define NHALO (LR*LC)      // 308
#define NRING 180          // NHALO - 8*16 interior
#define NBLK 200
#define NTHR 640
#define EPSF 1e-20f

// epoch word encoding: hi16 = tag, lo16 = seq (it+1). Any hi16 != tag -> seq 0.
// Tag bytes differ (0x5E vs 0xED) so NO byte-uniform poison can alias it.
#define EPTAG   0x5EED0000u
#define EPMASK  0xFFFF0000u

// bar layout (u32 words): epoch[b] at word 32+b*32 (128B stride); word 0 unused
#define EPW(b) (32 + (b)*32)

#define SZ_A    30720
#define OFF_WB  SZ_A
#define SHM_SZ  (SZ_A + 25*128*8)   // 56,320

__device__ __forceinline__ float fast_rcp(float x) { return __builtin_amdgcn_rcpf(x); }

__device__ __forceinline__ float smx0(float q0, float q1) {
    const float m  = fmaxf(q0, q1);
    const float e0 = __expf(q0 - m);
    const float e1 = __expf(q1 - m);
    return e0 * fast_rcp(e0 + e1);
}

__device__ __forceinline__ unsigned ep_decode(unsigned w) {
    return ((w & EPMASK) == EPTAG) ? (w & 0xFFFFu) : 0u;
}

__global__ void __launch_bounds__(NTHR) crf_kernel(
        const float* __restrict__ u,
        const float* __restrict__ rgb,
        const float* __restrict__ sw,
        const float* __restrict__ bw,
        const float* __restrict__ compat,
        unsigned long long* __restrict__ gsmA,   // ping-pong sm0 fields (f16x4)
        unsigned long long* __restrict__ gsmB,
        unsigned* __restrict__ bar,
        float* __restrict__ out) {
    __shared__ __align__(16) char shm[SHM_SZ];
    __shared__ float Msh[960];                   // 20x48 rows [Ms|Mb|RS|pad]
    __shared__ float rowsum[NC];
    __shared__ int   diagflag;
    float4*   rgbL = (float4*)shm;               // prologue only (region A)
    float4v*  smF  = (float4v*)shm;              // per-iter sm0 halo, f32 (region A)
    float*    accF = (float*)shm;                // general-path epilogue (region A)
    unsigned* wbW  = (unsigned*)(shm + OFF_WB);
    const uint2* wbP = (const uint2*)(shm + OFF_WB);

    constexpr float WSPC[49] = {
        0.36787944f,0.48567179f,0.57375342f,0.60653066f,0.57375342f,0.48567179f,0.36787944f,
        0.48567179f,0.64118039f,0.75746513f,0.80073740f,0.75746513f,0.64118039f,0.48567179f,
        0.57375342f,0.75746513f,0.89483932f,0.94595947f,0.89483932f,0.75746513f,0.57375342f,
        0.60653066f,0.80073740f,0.94595947f,1.00000000f,0.94595947f,0.80073740f,0.60653066f,
        0.57375342f,0.75746513f,0.89483932f,0.94595947f,0.89483932f,0.75746513f,0.57375342f,
        0.48567179f,0.64118039f,0.75746513f,0.80073740f,0.75746513f,0.64118039f,0.48567179f,
        0.36787944f,0.48567179f,0.57375342f,0.60653066f,0.57375342f,0.48567179f,0.36787944f };

    const int tid = threadIdx.x;
    const int px  = tid & 127;
    const int g   = tid >> 7;
    const int r   = px >> 4, c = px & 15;
    const int ti0 = blockIdx.y * TR, tj0 = blockIdx.x * TC;
    const int gp  = (ti0 + r) * WW + (tj0 + c);
    const int ctr  = (r + SPAN) * LCP   + (c + SPAN);   // rgb halo center
    const int ctrF = (r + SPAN) * LCP_F + (c + SPAN);   // f32 sm halo center
    const int ku  = 4 * g;
    const int bid = blockIdx.y * 10 + blockIdx.x;    // grid (10, 20)

    // neighbor epochs to wait on (pad missing neighbors with own bid)
    int nb[8];
    {
        const int bx = blockIdx.x, by = blockIdx.y;
        int k = 0;
        #pragma unroll
        for (int dy2 = -1; dy2 <= 1; ++dy2)
            #pragma unroll
            for (int dx2 = -1; dx2 <= 1; ++dx2) {
                if (dx2 == 0 && dy2 == 0) continue;
                const int nx = bx + dx2, ny = by + dy2;
                nb[k++] = ((unsigned)nx < 10u && (unsigned)ny < 20u) ? (ny*10 + nx) : bid;
            }
    }

    if (tid == 0) diagflag = 1;

    // ---- earliest possible: own unaries -> sm0 -> publish (iteration 0) ----
    float uv0[4], uv1[4];
    #pragma unroll
    for (int i = 0; i < 4; ++i) {
        const int ch = 4*g + i;
        uv0[i] = (ch < NC) ? u[(size_t)gp * NC + ch] : 0.0f;
        uv1[i] = (ch < NC) ? u[((size_t)NPIX + gp) * NC + ch] : 0.0f;
    }
    half4 sh;
    float smv[4];
    #pragma unroll
    for (int i = 0; i < 4; ++i) {
        smv[i] = smx0(uv0[i], uv1[i]);
        sh[i]  = (_Float16)smv[i];
    }
    {
        unsigned long long u64; __builtin_memcpy(&u64, &sh, 8);
        __hip_atomic_store(&gsmA[g * NPIX + gp], u64,
                           __ATOMIC_RELAXED, __HIP_MEMORY_SCOPE_AGENT);
    }

    if (tid < NC) {
        float rs = 0.0f;
        for (int cb = 0; cb < NC; ++cb) rs += sw[tid*NC + cb] + bw[tid*NC + cb];
        rowsum[tid] = rs;
    }
    __syncthreads();             // drains ALL waves' sm0 publishes (vmcnt 0)
    if (tid == 0)                // epoch visible to neighbors during prologue
        __hip_atomic_store(&bar[EPW(bid)], EPTAG | 1u,
                           __ATOMIC_RELAXED, __HIP_MEMORY_SCOPE_AGENT);

    // ---- phase 0: M = [compat@sw | compat@bw | RS] into LDS, O(19)/entry ----
    for (int e = tid; e < 960; e += NTHR) {
        const int k = e / 48, cc2 = e % 48;
        float acc = 0.0f;
        if (k < NC) {
            if (cc2 < NC) {
                for (int j = 0; j < NC; ++j) acc += compat[k*NC + j] * sw[j*NC + cc2];
            } else if (cc2 >= 20 && cc2 < 20 + NC) {
                const int cb = cc2 - 20;
                for (int j = 0; j < NC; ++j) acc += compat[k*NC + j] * bw[j*NC + cb];
            } else if (cc2 == 40) {
                for (int j = 0; j < NC; ++j) acc += compat[k*NC + j] * rowsum[j];
            }
        }
        Msh[e] = acc;
        bool off = false;
        if (k < NC) {
            if (cc2 < NC && cc2 != k && acc != 0.0f) off = true;
            if (cc2 >= 20 && cc2 < 20 + NC && (cc2 - 20) != k && acc != 0.0f) off = true;
        }
        if (off) atomicAnd(&diagflag, 0);
    }
    __syncthreads();

    float dsv[4], dbv[4];
    #pragma unroll
    for (int i = 0; i < 4; ++i) {
        dsv[i] = Msh[(ku + i) * 48 + (ku + i)];
        dbv[i] = Msh[(ku + i) * 48 + 20 + (ku + i)];
    }
    const bool isdiag = (diagflag != 0);

    // ---- phase 1: rgb halo, both batches ----
    for (int e = tid; e < 2 * NHALO; e += NTHR) {
        const int bb = e / NHALO, pos = e % NHALO;
        const int hr = pos / LC, hc = pos % LC;
        const int yi = ti0 - SPAN + hr, xj = tj0 - SPAN + hc;
        float4 rv = make_float4(0.f, 0.f, 0.f, 0.f);
        if ((unsigned)yi < HH && (unsigned)xj < WW) {
            const float* p = rgb + ((size_t)(bb * NPIX) + yi * WW + xj) * 3;
            rv = make_float4(p[0]*(1.f/160.f), p[1]*(1.f/160.f), p[2]*(1.f/160.f), 1.f);
        }
        rgbL[(bb ? HSTRIDE : 0) + hr * LCP + hc] = rv;
    }
    __syncthreads();

    // ---- phase 2a: bilateral weights (tap-subset per group) -> LDS pairs ----
    {
        const float4 cv0 = rgbL[ctr];
        const float4 cv1 = rgbL[HSTRIDE + ctr];
        const int tapb = g * 10;
        const int ntap = (g == 4) ? 9 : 10;
        for (int i = 0; i < ntap; ++i) {
            const int t = tapb + i;
            const int dx = t / 7 - SPAN, dy = t % 7 - SPAN;
            const int n = ctr + dx * LCP + dy;
            const float4 nv0 = rgbL[n];
            const float4 nv1 = rgbL[HSTRIDE + n];
            const float wsm = __expf(-(float)(dx*dx + dy*dy) * (1.f/18.f)) * nv0.w;
            const float dr0 = cv0.x-nv0.x, dg0 = cv0.y-nv0.y, db0 = cv0.z-nv0.z;
            const float dr1 = cv1.x-nv1.x, dg1 = cv1.y-nv1.y, db1 = cv1.z-nv1.z;
            const float wb0 = wsm * __expf(-0.5f*(dr0*dr0+dg0*dg0+db0*db0));
            const float wb1 = wsm * __expf(-0.5f*(dr1*dr1+dg1*dg1+db1*db1));
            half2f hw = {(_Float16)wb0, (_Float16)wb1};
            unsigned uw; __builtin_memcpy(&uw, &hw, 4);
            wbW[(t >> 1) * 256 + px * 2 + (t & 1)] = uw;
        }
        if (g == 4) wbW[24 * 256 + px * 2 + 1] = 0u;
    }
    __syncthreads();

    // ---- phase 2b: per-pixel inverse norms ----
    float snI, bnI0, bnI1;
    {
        float sn = 0.f, bn0 = 0.f, bn1 = 0.f;
        #pragma unroll
        for (int t = 0; t < 49; ++t) {
            const unsigned uw = wbW[(t >> 1) * 256 + px * 2 + (t & 1)];
            half2f hw; __builtin_memcpy(&hw, &uw, 4);
            bn0 += (float)hw.x; bn1 += (float)hw.y;
            const int dx = t / 7 - SPAN, dy = t % 7 - SPAN;
            const int yi = ti0 + r + dx, xj = tj0 + c + dy;
            sn += (((unsigned)yi < HH) && ((unsigned)xj < WW)) ? WSPC[t] : 0.0f;
        }
        snI  = fast_rcp(sn + EPSF);
        bnI0 = fast_rcp(bn0 + EPSF);
        bnI1 = fast_rcp(bn1 + EPSF);
    }

    for (int it = 0; it < 5; ++it) {
        // drain tail publishes of this iteration (vmcnt 0) + all waves past
        // previous LDS reads -> region A reusable
        __syncthreads();

        // interior self-write from f32 registers (overlaps tid0's poll)
        {
            const float4v sv = {smv[0], smv[1], smv[2], smv[3]};
            smF[g * HS_F + ctrF] = sv;
        }

        // ---- neighbor-only epoch sync (tag-encoded, poison-robust) ----
        if (tid == 0) {
            const unsigned seq = (unsigned)(it + 1);
            if (it > 0)
                __hip_atomic_store(&bar[EPW(bid)], EPTAG | seq,
                                   __ATOMIC_RELAXED, __HIP_MEMORY_SCOPE_AGENT);
            unsigned mn;
            do {
                mn = 0xFFFFu;
                #pragma unroll
                for (int k = 0; k < 8; ++k) {
                    const unsigned w = __hip_atomic_load(&bar[EPW(nb[k])],
                                                         __ATOMIC_RELAXED, __HIP_MEMORY_SCOPE_AGENT);
                    const unsigned e = ep_decode(w);
                    mn = (e < mn) ? e : mn;
                }
                if (mn < seq) __builtin_amdgcn_s_sleep(1);
            } while (mn < seq);
        }
        __syncthreads();

        // ---- stage: ring from gsm (f16 -> f32 once) ----
        const unsigned long long* gsrc = ((it & 1) ? gsmB : gsmA);
        #pragma unroll
        for (int k2 = 0; k2 < 2; ++k2) {
            const int e = tid + NTHR * k2;
            if (e < NG * NRING) {
                const int sg = e / NRING, re = e - sg * NRING;
                int hr, hc;
                if (re < 66)        { hr = re / 22;          hc = re % 22; }
                else if (re < 132)  { const int t2 = re - 66;  hr = 11 + t2 / 22; hc = t2 % 22; }
                else                { const int t2 = re - 132; hr = 3 + t2 / 6;
                                      const int s = t2 % 6;    hc = (s < 3) ? s : s + 16; }
                const int yi = ti0 - SPAN + hr, xj = tj0 - SPAN + hc;
                float4v fv = (float4v)0.0f;
                if ((unsigned)yi < HH && (unsigned)xj < WW) {
                    const unsigned long long raw =
                        __hip_atomic_load(&gsrc[sg * NPIX + yi * WW + xj],
                                          __ATOMIC_RELAXED, __HIP_MEMORY_SCOPE_AGENT);
                    half4 hv; __builtin_memcpy(&hv, &raw, 8);
                    fv = (float4v){(float)hv[0], (float)hv[1], (float)hv[2], (float)hv[3]};
                }
                smF[sg * HS_F + hr * LCP_F + hc] = fv;
            }
        }
        __syncthreads();

        // ---- 49 taps as 24 pairs + 1 (f32 LDS reads, no per-tap cvt) ----
        float4v sAv = (float4v)0.0f, b0a = (float4v)0.0f, b1a = (float4v)0.0f;
        const float4v* pl = smF + g * HS_F;
        #pragma unroll
        for (int i = 0; i < 24; ++i) {
            const uint2 wp = wbP[i * 128 + px];
            #pragma unroll
            for (int s = 0; s < 2; ++s) {
                const int t = 2*i + s;
                const int dx = t / 7 - SPAN, dy = t % 7 - SPAN;
                half2f hw; __builtin_memcpy(&hw, s ? &wp.y : &wp.x, 4);
                const float w0 = (float)hw.x, w1 = (float)hw.y;
                const float4v f = pl[ctrF + dx*LCP_F + dy];
                sAv += WSPC[t] * f;
                b0a += w0 * f;
                b1a += w1 * f;
            }
        }
        {   // tap 48
            const uint2 wp = wbP[24 * 128 + px];
            half2f hw; __builtin_memcpy(&hw, &wp.x, 4);
            const float w0 = (float)hw.x, w1 = (float)hw.y;
            const float4v f = pl[ctrF + SPAN*LCP_F + SPAN];
            sAv += WSPC[48] * f;
            b0a += w0 * f;
            b1a += w1 * f;
        }

        float q0v[4], q1v[4];
        if (isdiag) {
            #pragma unroll
            for (int i = 0; i < 4; ++i) {
                const float sAn = sAv[i] * snI;
                const float b0n = b0a[i] * bnI0;
                const float b1x = b1a[i] * bnI1;
                q0v[i] = uv0[i] - dsv[i]*sAn - dbv[i]*b0n;
                q1v[i] = uv1[i] - (dsv[i] + dbv[i]) + dsv[i]*sAn + dbv[i]*b1x;
            }
        } else {
            __syncthreads();   // smF dead -> region A becomes accF
            #pragma unroll
            for (int i = 0; i < 4; ++i) {
                accF[(4*g + i) * NPXT + px]      = sAv[i] * snI;
                accF[(20 + 4*g + i) * NPXT + px] = b0a[i] * bnI0;
                accF[(40 + 4*g + i) * NPXT + px] = b1a[i] * bnI1;
            }
            __syncthreads();
            float t1[4] = {0,0,0,0}, t2[4] = {0,0,0,0}, t3[4] = {0,0,0,0};
            #pragma unroll
            for (int cc = 0; cc < 20; ++cc) {
                const float sv  = accF[cc * NPXT + px];
                const float b0v = accF[(20 + cc) * NPXT + px];
                const float b1v = accF[(40 + cc) * NPXT + px];
                #pragma unroll
                for (int i = 0; i < 4; ++i) {
                    const float* mk = Msh + (ku + i) * 48;
                    t1[i] += mk[cc] * sv;
                    t2[i] += mk[20 + cc] * b0v;
                    t3[i] += mk[20 + cc] * b1v;
                }
            }
            #pragma unroll
            for (int i = 0; i < 4; ++i) {
                const float rs = Msh[(ku + i) * 48 + 40];
                q0v[i] = uv0[i] - t1[i] - t2[i];
                q1v[i] = uv1[i] - rs + t1[i] + t3[i];
            }
        }

        if (it == 4) {
            #pragma unroll
            for (int i = 0; i < 4; ++i) {
                const int ch = 4*g + i;
                if (ch < NC) {
                    out[(size_t)gp * NC + ch]          = q0v[i];
                    out[((size_t)NPIX + gp) * NC + ch] = q1v[i];
                }
            }
        } else {
            // sm for iteration it+1: f32 in regs (interior) + f16 publish (halo)
            #pragma unroll
            for (int i = 0; i < 4; ++i) {
                smv[i] = smx0(q0v[i], q1v[i]);
                sh[i]  = (_Float16)smv[i];
            }
            unsigned long long u64; __builtin_memcpy(&u64, &sh, 8);
            unsigned long long* gdst = (((it + 1) & 1) ? gsmB : gsmA);
            __hip_atomic_store(&gdst[g * NPIX + gp], u64,
                               __ATOMIC_RELAXED, __HIP_MEMORY_SCOPE_AGENT);
        }
    }
}

extern "C" void kernel_launch(void* const* d_in, const int* in_sizes, int n_in,
                              void* d_out, int out_size, void* d_ws, size_t ws_size,
                              hipStream_t stream) {
    const float* u      = (const float*)d_in[0];
    const float* rgb    = (const float*)d_in[1];
    const float* sw     = (const float*)d_in[2];
    const float* bw     = (const float*)d_in[3];
    const float* compat = (const float*)d_in[4];
    float* out = (float*)d_out;

    unsigned long long* gsmA = (unsigned long long*)d_ws;              // 1,024,000 B
    unsigned long long* gsmB = (unsigned long long*)((char*)d_ws + 1024000);
    unsigned* bar = (unsigned*)((char*)d_ws + 2048000);                // epochs (tag-encoded)

    crf_kernel<<<dim3(WW/TC, HH/TR, 1), dim3(NTHR), 0, stream>>>(
        u, rgb, sw, bw, compat, gsmA, gsmB, bar, out);
}